// Round 8
// baseline (120.145 us; speedup 1.0000x reference)
//
#include <hip/hip_runtime.h>

typedef _Float16 half8 __attribute__((ext_vector_type(8)));
typedef _Float16 half4 __attribute__((ext_vector_type(4)));
typedef float    f32x4 __attribute__((ext_vector_type(4)));

#define T_TOK 16384
#define D_DIM 4096
#define E_EXP 128
#define CAP   256
#define BM    32
#define NT    32   // macro K-steps per pipe, BK=64 each (K per pipe = 2048)

// A LDS: [pipe][buf][row 0..31][256 B]. Per row: [ks=0 128B][ks=1 128B].
// Within each 128B half: 8 chunks of 16B; h data at chunk (g ^ (row&7)),
// m data at chunk ((g|4) ^ (row&7)), g = k-group 0..3. Conflict-free for the
// 8-lane HW phases of both ds_write_b64 staging and ds_read_b128 reads.
#define A_BUF_SZ  8192
#define A_PIPE_SZ 16384

// ---------------------------------------------------------------------------
// Kernel 0: wg (fp32) -> K-step-tiled split-fp16 planes, scaled by 64.
// Step s (BK=32) block: h plane 8192 B | m plane 8192 B; expert e at e*64 B.
// ---------------------------------------------------------------------------
__global__ __launch_bounds__(256) void prep_wt(
    const float* __restrict__ wg, _Float16* __restrict__ wt)
{
    const int t = blockIdx.x * 256 + threadIdx.x;  // 65536 threads
    const int c = t & 3;
    const int e = (t >> 2) & 127;
    const int s = t >> 9;

    const float* src = wg + (size_t)e * D_DIM + s * 32 + c * 8;
    const f32x4 v0 = *reinterpret_cast<const f32x4*>(src);
    const f32x4 v1 = *reinterpret_cast<const f32x4*>(src + 4);

    half8 h, m;
#pragma unroll
    for (int j = 0; j < 4; j++) {
        float sv = v0[j] * 64.0f;
        _Float16 hh = (_Float16)sv;
        h[j] = hh; m[j] = (_Float16)(sv - (float)hh);
        sv = v1[j] * 64.0f;
        hh = (_Float16)sv;
        h[4 + j] = hh; m[4 + j] = (_Float16)(sv - (float)hh);
    }
    _Float16* dst = wt + (size_t)s * 8192 + e * 32 + c * 8;
    *reinterpret_cast<half8*>(dst)        = h;
    *reinterpret_cast<half8*>(dst + 4096) = m;
}

// ---------------------------------------------------------------------------
// Kernel A: dual-K-pipe MFMA GEMM + fused gate epilogue + idx1 histogram.
// 512 thr = 8 waves; waves 0-3 = K-half 0, waves 4-7 = K-half 1; BK=64/step.
// A: x -> regs (2 steps ahead) -> fp16 h/m split -> XOR-swizzled LDS dbuf.
// B: K-tiled wt planes -> registers, PREFETCHED ONE MACRO-STEP AHEAD so the
//    L2 latency hides under the previous step's MFMA cluster.
// Barrier = s_waitcnt lgkmcnt(0) + s_barrier (vmem stays in flight).
// ---------------------------------------------------------------------------
__global__ __launch_bounds__(512, 4) void gemm_gate(
    const float* __restrict__ x, const _Float16* __restrict__ wt,
    float* __restrict__ out, float* __restrict__ me, int* __restrict__ cnt1)
{
    __shared__ char smem[2 * A_PIPE_SZ];   // 32 KB A tiles
    __shared__ float lg[BM][E_EXP + 1];    // 16.5 KB logits

    const int tid  = threadIdx.x;
    const int row0 = blockIdx.x * BM;
    const int lane = tid & 63;
    const int w    = tid >> 6;
    const int kp   = w >> 2;     // K-pipe 0/1
    const int wl   = w & 3;      // expert group: experts wl*32 .. +32
    const int lr   = lane & 15;
    const int lq   = lane >> 4;

    // ---- A staging role: threads 0-255 stage pipe 0, 256-511 pipe 1 ----
    const int sp   = tid >> 8;
    const int srow = (tid >> 3) & 31;
    const int sg   = tid & 7;
    const float* xA = x + (size_t)(row0 + srow) * D_DIM + sp * 2048 + sg * 4;
    const int awr_h = sp * A_PIPE_SZ + srow * 256 +
                      (((sg >> 1)    ) ^ (srow & 7)) * 16 + (sg & 1) * 8;
    const int awr_m = sp * A_PIPE_SZ + srow * 256 +
                      (((sg >> 1) | 4) ^ (srow & 7)) * 16 + (sg & 1) * 8;

    // ---- A fragment read offsets (pipe kp) ----
    const int ah_ch = ((lq    ) ^ (lr & 7)) * 16;
    const int am_ch = ((lq | 4) ^ (lr & 7)) * 16;
    const char* const ard = smem + kp * A_PIPE_SZ;

    // ---- B fragment base: sub-step s = kp*64 + 2t + ks ----
    const _Float16* const wtB =
        wt + (size_t)(kp * 64) * 8192 + (wl * 32 + lr) * 32 + lq * 8;

    f32x4 acc[2][2];
#pragma unroll
    for (int i = 0; i < 2; i++)
#pragma unroll
        for (int j = 0; j < 2; j++) acc[i][j] = (f32x4)0.0f;

#define CONV_WRITE(av0, av1, buf)                                             \
    {                                                                         \
        half4 h0, m0, h1, m1;                                                 \
        _Pragma("unroll") for (int j = 0; j < 4; j++) {                       \
            _Float16 hh = (_Float16)av0[j];                                   \
            h0[j] = hh; m0[j] = (_Float16)(av0[j] - (float)hh);               \
            hh = (_Float16)av1[j];                                            \
            h1[j] = hh; m1[j] = (_Float16)(av1[j] - (float)hh);               \
        }                                                                     \
        char* const wb = smem + (buf) * A_BUF_SZ;                             \
        *reinterpret_cast<half4*>(wb + awr_h)       = h0;                     \
        *reinterpret_cast<half4*>(wb + awr_m)       = m0;                     \
        *reinterpret_cast<half4*>(wb + awr_h + 128) = h1;                     \
        *reinterpret_cast<half4*>(wb + awr_m + 128) = m1;                     \
    }

#define LOAD_B(Bh0, Bm0, Bh1, Bm1, t)                                         \
    {                                                                         \
        const _Float16* bp = wtB + (size_t)(2 * ((t) & (NT - 1))) * 8192;     \
        _Pragma("unroll") for (int cf = 0; cf < 2; cf++) {                    \
            Bh0[cf] = *reinterpret_cast<const half8*>(bp + cf * 512);         \
            Bm0[cf] = *reinterpret_cast<const half8*>(bp + 4096 + cf * 512);  \
            Bh1[cf] = *reinterpret_cast<const half8*>(bp + 8192 + cf * 512);  \
            Bm1[cf] = *reinterpret_cast<const half8*>(bp + 12288 + cf * 512); \
        }                                                                     \
    }

#define BAR()                                                                 \
    asm volatile("s_waitcnt lgkmcnt(0)" ::: "memory");                        \
    __builtin_amdgcn_sched_barrier(0);                                        \
    __builtin_amdgcn_s_barrier();                                             \
    __builtin_amdgcn_sched_barrier(0);

#define SUBSTEP(cur, ks, Bh, Bm)                                              \
    {                                                                         \
        half8 Ah[2], Am[2];                                                   \
        _Pragma("unroll") for (int rf = 0; rf < 2; rf++) {                    \
            const char* ab = ard + (cur) * A_BUF_SZ +                         \
                             (rf * 16 + lr) * 256 + (ks) * 128;               \
            Ah[rf] = *reinterpret_cast<const half8*>(ab + ah_ch);             \
            Am[rf] = *reinterpret_cast<const half8*>(ab + am_ch);             \
        }                                                                     \
        _Pragma("unroll") for (int rf = 0; rf < 2; rf++)                      \
            _Pragma("unroll") for (int cf = 0; cf < 2; cf++) {                \
                acc[rf][cf] = __builtin_amdgcn_mfma_f32_16x16x32_f16(         \
                    Am[rf], Bh[cf], acc[rf][cf], 0, 0, 0);                    \
                acc[rf][cf] = __builtin_amdgcn_mfma_f32_16x16x32_f16(         \
                    Ah[rf], Bm[cf], acc[rf][cf], 0, 0, 0);                    \
                acc[rf][cf] = __builtin_amdgcn_mfma_f32_16x16x32_f16(         \
                    Ah[rf], Bh[cf], acc[rf][cf], 0, 0, 0);                    \
            }                                                                 \
    }

// One macro-step: issue A(t+2) + B(t+1) loads first, then compute step t
// from the registers/LDS filled in earlier steps, then stage A(t+1), barrier.
#define STEP(cur, A0C, A1C, A0N, A1N, CH0, CM0, CH1, CM1,                     \
             NH0, NM0, NH1, NM1, t)                                           \
    {                                                                         \
        const int kn = (((t) + 2) & (NT - 1)) * 64;                           \
        A0N = *reinterpret_cast<const f32x4*>(xA + kn);                       \
        A1N = *reinterpret_cast<const f32x4*>(xA + kn + 32);                  \
        LOAD_B(NH0, NM0, NH1, NM1, (t) + 1);                                  \
        SUBSTEP(cur, 0, CH0, CM0);                                            \
        SUBSTEP(cur, 1, CH1, CM1);                                            \
        CONV_WRITE(A0C, A1C, (cur) ^ 1);                                      \
        BAR();                                                                \
    }

    f32x4 avA0, avA1, avB0, avB1;
    half8 BhA0[2], BmA0[2], BhA1[2], BmA1[2];
    half8 BhB0[2], BmB0[2], BhB1[2], BmB1[2];

    // ---- prologue: A(0) -> buf0; A(1) -> regs; B(0) -> reg set A ----
    {
        const f32x4 a00 = *reinterpret_cast<const f32x4*>(xA);
        const f32x4 a01 = *reinterpret_cast<const f32x4*>(xA + 32);
        avA0 = *reinterpret_cast<const f32x4*>(xA + 64);
        avA1 = *reinterpret_cast<const f32x4*>(xA + 96);
        LOAD_B(BhA0, BmA0, BhA1, BmA1, 0);
        CONV_WRITE(a00, a01, 0);
        BAR();
    }

    // ---- main loop: 32 macro-steps, 2 per iteration (static indices) ----
    for (int t = 0; t < NT; t += 2) {
        STEP(0, avA0, avA1, avB0, avB1,
             BhA0, BmA0, BhA1, BmA1, BhB0, BmB0, BhB1, BmB1, t);
        STEP(1, avB0, avB1, avA0, avA1,
             BhB0, BmB0, BhB1, BmB1, BhA0, BmA0, BhA1, BmA1, t + 1);
    }

#undef STEP
#undef SUBSTEP
#undef BAR
#undef LOAD_B
#undef CONV_WRITE

    // ---- merge the two K-pipes into lg, scaled by 1/64 ----
    if (kp == 1) {
#pragma unroll
        for (int rf = 0; rf < 2; rf++)
#pragma unroll
            for (int cf = 0; cf < 2; cf++)
#pragma unroll
                for (int r = 0; r < 4; r++)
                    lg[rf * 16 + lq * 4 + r][wl * 32 + cf * 16 + lr] =
                        acc[rf][cf][r] * 0.015625f;
    }
    __syncthreads();
    if (kp == 0) {
#pragma unroll
        for (int rf = 0; rf < 2; rf++)
#pragma unroll
            for (int cf = 0; cf < 2; cf++)
#pragma unroll
                for (int r = 0; r < 4; r++)
                    lg[rf * 16 + lq * 4 + r][wl * 32 + cf * 16 + lr] +=
                        acc[rf][cf][r] * 0.015625f;
    }
    __syncthreads();

    // ---- gate epilogue ----
    if (tid < BM) {
        const int r = tid;
        const int t = row0 + r;
        float m1 = -1e30f, m2 = -1e30f;
        int   i1 = 0, i2 = 0;
        for (int e = 0; e < E_EXP; e++) {
            const float v = lg[r][e];
            if (v > m1)      { m2 = m1; i2 = i1; m1 = v; i1 = e; }
            else if (v > m2) { m2 = v; i2 = e; }
        }
        float s = 0.0f;
        for (int e = 0; e < E_EXP; e++) s += __expf(lg[r][e] - m1);
        const float inv = 1.0f / s;

        out[3 + 0 * T_TOK + t] = (float)i1;
        out[3 + 1 * T_TOK + t] = (float)i2;
        out[3 + 4 * T_TOK + t] = inv;
        out[3 + 5 * T_TOK + t] = __expf(m2 - m1) * inv;
        atomicAdd(&cnt1[i1], 1);

        for (int e = 0; e < E_EXP; e++)
            lg[r][e] = __expf(lg[r][e] - m1) * inv;
    }
    __syncthreads();

    if (tid < E_EXP) {
        float s = 0.0f;
        for (int r = 0; r < BM; r++) s += lg[r][tid];
        atomicAdd(&me[tid], s);
    }
}

// ---------------------------------------------------------------------------
// Kernel B: per-expert rank. 256 blocks x 1024 thr: blocks 0-127 scan idx1;
// blocks 128-255 scan idx2 starting at base = cnt1[e] (from gemm histogram).
// ---------------------------------------------------------------------------
__global__ __launch_bounds__(1024) void rank_kernel(
    float* __restrict__ out, const int* __restrict__ cnt1)
{
    const int  e      = blockIdx.x & 127;
    const bool second = blockIdx.x >= 128;
    const int  tid    = threadIdx.x;
    const int  lane   = tid & 63;
    const int  w      = tid >> 6;   // 0..15

    __shared__ int wtot[16];

    const float* idxA = out + 3 + (second ? T_TOK : 0);
    float* loc = out + 3 + (second ? 3 * T_TOK : 2 * T_TOK);

    const unsigned long long below = (1ull << lane) - 1ull;
    int base = second ? cnt1[e] : 0;

    for (int t0 = 0; t0 < T_TOK; t0 += 1024) {
        const int t = t0 + tid;
        const int f = ((int)idxA[t] == e);
        const unsigned long long m = __ballot(f);
        const int pre = __popcll(m & below);
        const int tot = __popcll(m);
        if (lane == 0) wtot[w] = tot;
        __syncthreads();
        int off = 0, all = 0;
#pragma unroll
        for (int i = 0; i < 16; i++) {
            const int v = wtot[i];
            if (i < w) off += v;
            all += v;
        }
        if (f) {
            const int rank = base + off + pre;
            loc[t] = (rank < CAP) ? (float)rank : 0.0f;
        }
        base += all;
        __syncthreads();
    }
}

// ---------------------------------------------------------------------------
// Kernel C: l_aux = sum(me * min(cnt1,CAP)) * E/(T*T); plus constants.
// ---------------------------------------------------------------------------
__global__ __launch_bounds__(128) void finalize_kernel(
    const float* __restrict__ me, const int* __restrict__ cnt1,
    float* __restrict__ out)
{
    __shared__ float red[2];
    const int tid = threadIdx.x;
    const int c = cnt1[tid];
    float p = me[tid] * (float)((c < CAP) ? c : CAP);
#pragma unroll
    for (int o = 32; o > 0; o >>= 1) p += __shfl_down(p, o);
    if ((tid & 63) == 0) red[tid >> 6] = p;
    __syncthreads();
    if (tid == 0) {
        const float tot = red[0] + red[1];
        out[0] = tot * ((float)E_EXP / ((float)T_TOK * (float)T_TOK));
        out[1] = (float)CAP;
        out[2] = (float)E_EXP;
    }
}

extern "C" void kernel_launch(void* const* d_in, const int* in_sizes, int n_in,
                              void* d_out, int out_size, void* d_ws, size_t ws_size,
                              hipStream_t stream)
{
    const float* x  = (const float*)d_in[0];
    const float* wg = (const float*)d_in[1];
    float* out = (float*)d_out;

    float* me   = (float*)d_ws;                      // 128 floats
    int*   cnt1 = (int*)((char*)d_ws + 512);         // 128 ints
    _Float16* wt = (_Float16*)((char*)d_ws + 1024);  // 2 MB K-tiled planes

    hipMemsetAsync(d_ws, 0, 1024, stream);
    prep_wt<<<256, 256, 0, stream>>>(wg, wt);
    gemm_gate<<<T_TOK / BM, 512, 0, stream>>>(x, wt, out, me, cnt1);
    rank_kernel<<<2 * E_EXP, 1024, 0, stream>>>(out, cnt1);
    finalize_kernel<<<1, 128, 0, stream>>>(me, cnt1, out);
}